// Round 9
// baseline (131.690 us; speedup 1.0000x reference)
//
#include <hip/hip_runtime.h>

#define NB 16
#define NC 128
#define NH 8192
#define EPSN 1e-5f

typedef __attribute__((ext_vector_type(8))) short short8;
typedef __attribute__((ext_vector_type(4))) float f32x4;

__device__ inline unsigned short f2bf(float f) {
  unsigned int u = __builtin_bit_cast(unsigned int, f);
  u = u + 0x7FFFu + ((u >> 16) & 1u);
  return (unsigned short)(u >> 16);
}

// ---------------------------------------------------------------------------
// alpha[b,h] = sigmoid( sum_v cat(corr,coh)[b,v,h]*fcw[v] + fcb )
// Thread = (cg 0..7, quad 0..31) over a (b, 128-px) tile; 32 channels/thread
// as 4 hand-unrolled batches of 8 float4 loads through DISTINCT named arrays
// (peak 16 loads in flight). __launch_bounds__(256,4) caps VGPR at 128 so the
// compiler keeps the batches resident (round-8 failure: VGPR=32 -> ~1-2 loads
// in flight -> latency-bound at 1.5 TB/s).
__global__ __launch_bounds__(256, 4) void alpha_kernel(
    const float* __restrict__ corr, const float* __restrict__ coh,
    const float* __restrict__ fcw, const float* __restrict__ fcb,
    float* __restrict__ alpha) {
  __shared__ float part[8][128];
  const int t = threadIdx.x;
  const int b = blockIdx.x >> 6;
  const int h0 = (blockIdx.x & 63) << 7;  // 128-px tile
  const int cg = t >> 5;                  // 0..7
  const int quad = t & 31;                // px = quad*4

  const float* pc = corr + ((size_t)(b * NC + cg * 8) << 13) + h0 + quad * 4;
  const float* ph = coh + ((size_t)(b * NC + cg * 8) << 13) + h0 + quad * 4;

  // weights for the 4 batches (8 each)
  float fw0[8], fw1[8], fw2[8], fw3[8];
#pragma unroll
  for (int k = 0; k < 2; ++k) {
    *(float4*)&fw0[k * 4] = *(const float4*)(fcw + cg * 8 + k * 4);
    *(float4*)&fw1[k * 4] = *(const float4*)(fcw + 64 + cg * 8 + k * 4);
    *(float4*)&fw2[k * 4] = *(const float4*)(fcw + 128 + cg * 8 + k * 4);
    *(float4*)&fw3[k * 4] = *(const float4*)(fcw + 192 + cg * 8 + k * 4);
  }

  float4 xa[8], xb[8], xc[8], xd[8];
#pragma unroll
  for (int j = 0; j < 8; ++j) xa[j] = *(const float4*)(pc + ((size_t)j << 13));
#pragma unroll
  for (int j = 0; j < 8; ++j)
    xb[j] = *(const float4*)(pc + ((size_t)(64 + j) << 13));

  float4 acc0 = {0, 0, 0, 0}, acc1 = {0, 0, 0, 0};

  // consume A (corr c=cg*8+j); issue C (coh c=cg*8+j)
#pragma unroll
  for (int j = 0; j < 8; ++j) xc[j] = *(const float4*)(ph + ((size_t)j << 13));
#pragma unroll
  for (int j = 0; j < 8; ++j) {
    acc0.x = fmaf(xa[j].x, fw0[j], acc0.x);
    acc0.y = fmaf(xa[j].y, fw0[j], acc0.y);
    acc0.z = fmaf(xa[j].z, fw0[j], acc0.z);
    acc0.w = fmaf(xa[j].w, fw0[j], acc0.w);
  }
  // consume B (corr c=64+cg*8+j); issue D (coh c=64+cg*8+j)
#pragma unroll
  for (int j = 0; j < 8; ++j)
    xd[j] = *(const float4*)(ph + ((size_t)(64 + j) << 13));
#pragma unroll
  for (int j = 0; j < 8; ++j) {
    acc1.x = fmaf(xb[j].x, fw1[j], acc1.x);
    acc1.y = fmaf(xb[j].y, fw1[j], acc1.y);
    acc1.z = fmaf(xb[j].z, fw1[j], acc1.z);
    acc1.w = fmaf(xb[j].w, fw1[j], acc1.w);
  }
  // consume C, D
#pragma unroll
  for (int j = 0; j < 8; ++j) {
    acc0.x = fmaf(xc[j].x, fw2[j], acc0.x);
    acc0.y = fmaf(xc[j].y, fw2[j], acc0.y);
    acc0.z = fmaf(xc[j].z, fw2[j], acc0.z);
    acc0.w = fmaf(xc[j].w, fw2[j], acc0.w);
  }
#pragma unroll
  for (int j = 0; j < 8; ++j) {
    acc1.x = fmaf(xd[j].x, fw3[j], acc1.x);
    acc1.y = fmaf(xd[j].y, fw3[j], acc1.y);
    acc1.z = fmaf(xd[j].z, fw3[j], acc1.z);
    acc1.w = fmaf(xd[j].w, fw3[j], acc1.w);
  }

  float4 s;
  s.x = acc0.x + acc1.x;
  s.y = acc0.y + acc1.y;
  s.z = acc0.z + acc1.z;
  s.w = acc0.w + acc1.w;
  *(float4*)&part[cg][quad * 4] = s;
  __syncthreads();
  if (t < 128) {
    float l = fcb[0];
#pragma unroll
    for (int pidx = 0; pidx < 8; ++pidx) l += part[pidx][t];
    alpha[b * NH + h0 + t] = 1.0f / (1.0f + __expf(-l));
  }
}

// ---------------------------------------------------------------------------
// agg = corr - alpha*feats ; accumulate per-(b,c) sum / sumsq for InstanceNorm1.
__global__ __launch_bounds__(256) void agg_kernel(
    const float* __restrict__ corr, const float* __restrict__ feats,
    const float* __restrict__ alpha, float* __restrict__ agg,
    float* __restrict__ stats) {
  int blk = blockIdx.x;  // B*C*4 = 8192 blocks, 2048 elems each
  int chunk = blk & 3;
  int bc = blk >> 2;
  int b = bc >> 7;
  size_t base = (size_t)bc * NH + chunk * 2048;
  const float* pa = alpha + (size_t)b * NH + chunk * 2048;
  int t = threadIdx.x;
  float s = 0.f, q = 0.f;
#pragma unroll
  for (int r = 0; r < 2; ++r) {
    int off = r * 1024 + t * 4;
    float4 cv = *(const float4*)(corr + base + off);
    float4 fv = *(const float4*)(feats + base + off);
    float4 av = *(const float4*)(pa + off);
    float4 g;
    g.x = cv.x - av.x * fv.x;
    g.y = cv.y - av.y * fv.y;
    g.z = cv.z - av.z * fv.z;
    g.w = cv.w - av.w * fv.w;
    *(float4*)(agg + base + off) = g;
    s += (g.x + g.y) + (g.z + g.w);
    q = fmaf(g.x, g.x, q);
    q = fmaf(g.y, g.y, q);
    q = fmaf(g.z, g.z, q);
    q = fmaf(g.w, g.w, q);
  }
#pragma unroll
  for (int m = 32; m >= 1; m >>= 1) {
    s += __shfl_xor(s, m);
    q += __shfl_xor(q, m);
  }
  __shared__ float red[8];
  int wid = t >> 6;
  if ((t & 63) == 0) {
    red[wid * 2] = s;
    red[wid * 2 + 1] = q;
  }
  __syncthreads();
  if (t == 0) {
    float S = (red[0] + red[2]) + (red[4] + red[6]);
    float Q = (red[1] + red[3]) + (red[5] + red[7]);
    atomicAdd(&stats[bc * 2], S);
    atomicAdd(&stats[bc * 2 + 1], Q);
  }
}

// ---------------------------------------------------------------------------
// Fold IN (per b,c) + analytic BN (per c) + gamma/beta into per-(b,c) affine.
__global__ void finalize_kernel(const float* __restrict__ stats,
                                const float* __restrict__ g,
                                const float* __restrict__ be,
                                float* __restrict__ scale,
                                float* __restrict__ shift) {
  int c = threadIdx.x;  // 128 threads, 1 block
  float mean[NB], rstd[NB];
  float bnacc = 0.f;
#pragma unroll
  for (int b = 0; b < NB; ++b) {
    float s = stats[(b * NC + c) * 2];
    float q = stats[(b * NC + c) * 2 + 1];
    float m = s * (1.f / NH);
    float v = fmaxf(q * (1.f / NH) - m * m, 0.f);
    float r = rsqrtf(v + EPSN);
    mean[b] = m;
    rstd[b] = r;
    bnacc += v * r * r;
  }
  float bnr = rsqrtf(bnacc * (1.f / NB) + EPSN);
  float gc = g[c], bec = be[c];
#pragma unroll
  for (int b = 0; b < NB; ++b) {
    float sc = rstd[b] * bnr * gc;
    scale[b * NC + c] = sc;
    shift[b * NC + c] = fmaf(-mean[b], sc, bec);
  }
}

// ---------------------------------------------------------------------------
// bf16-MFMA 1x1 conv with fused input affine+ReLU, tile-looped + pipelined.
//   Out[b,o,h] = sum_c relu(X[b,c,h]*scale[b,c]+shift[b,c]) * W[o,c] + bias[o]
// LDS layout (B-fragment order):
//   halfword idx = fragid*512 + sublane*8 + j
//   fragid = (h>>4)*4 + (c>>5), sublane = 16*((c>>3)&3) + (h&15), j = c&7
// XOR swizzle byte ^= ((byte>>7)&7)<<4 on BOTH ds_write and ds_read.
// Block = (b, 2 consecutive 64-h tiles). In-place safe: each block reads and
// writes only its own disjoint h-range.
template <bool DOSTATS>
__global__ __launch_bounds__(256) void conv_mfma_kernel(
    const float* X, const float* __restrict__ scale,
    const float* __restrict__ shift, const float* __restrict__ W,
    const float* __restrict__ bias, float* Out, float* __restrict__ stats) {
  __shared__ __align__(16) unsigned short sXf[8192];  // 16 frags x 1 KB
  __shared__ float ssum[NC], ssq[NC];
  const int t = threadIdx.x;
  const int b = blockIdx.x >> 6;             // 64 blocks per batch
  const int hbase = (blockIdx.x & 63) << 7;  // 128 h per block (2 tiles)
  const int lane = t & 63;
  const int wv = t >> 6;
  const int wo = wv >> 1;  // o-half: wo*64
  const int wh = wv & 1;   // h-half within tile: wh*32

  if (DOSTATS && t < NC) { ssum[t] = 0.f; ssq[t] = 0.f; }

  // staging ownership: 8 consecutive c x 4 consecutive h per thread
  const int cb = (t >> 4) << 3;  // 0,8,...,120
  const int hq = t & 15;         // local h = hq*4 + r
  const int fragw = ((hq >> 2) << 2) + (cb >> 5);
  const int sub0 = (((cb >> 3) & 3) << 4) + ((hq & 3) << 2);
  const unsigned swz = ((unsigned)(sub0 >> 3)) << 4;  // r-invariant
  const unsigned br = ((unsigned)(lane << 4)) ^ (((unsigned)(lane >> 3)) << 4);

  const float* Xb = X + ((size_t)(b * NC) << 13);
  float* Ob = Out + ((size_t)(b * NC) << 13);

  // ---- prologue: issue tile-0 loads first (critical path)
  float4 xv[8];
#pragma unroll
  for (int p = 0; p < 8; ++p)
    xv[p] = *(const float4*)(Xb + ((size_t)(cb + p) << 13) + hbase + hq * 4);

  float scv[8], shv[8];
#pragma unroll
  for (int p = 0; p < 8; ++p) {
    scv[p] = scale[b * NC + cb + p];
    shv[p] = shift[b * NC + cb + p];
  }

  // ---- W frags (A operand), loaded once per block
  short8 wfr[4][4];
  {
    const int orow = wo * 64 + (lane & 15);
    const int cbw = 8 * (lane >> 4);
#pragma unroll
    for (int m = 0; m < 4; ++m) {
#pragma unroll
      for (int k = 0; k < 4; ++k) {
        const float* p = W + (orow + m * 16) * NC + k * 32 + cbw;
        float4 lo = *(const float4*)p;
        float4 hi = *(const float4*)(p + 4);
        union { short8 s; unsigned short u[8]; } fr;
        fr.u[0] = f2bf(lo.x); fr.u[1] = f2bf(lo.y);
        fr.u[2] = f2bf(lo.z); fr.u[3] = f2bf(lo.w);
        fr.u[4] = f2bf(hi.x); fr.u[5] = f2bf(hi.y);
        fr.u[6] = f2bf(hi.z); fr.u[7] = f2bf(hi.w);
        wfr[m][k] = fr.s;
      }
    }
  }

  float as_[4][4], aq_[4][4];
  if (DOSTATS) {
#pragma unroll
    for (int m = 0; m < 4; ++m)
#pragma unroll
      for (int r = 0; r < 4; ++r) { as_[m][r] = 0.f; aq_[m][r] = 0.f; }
  }

  const int og = (lane >> 4) << 2;
  const int hcol = lane & 15;

  for (int tt = 0; tt < 2; ++tt) {
    // ---- convert + pack + 4x ds_write_b128 (swizzled)
#pragma unroll
    for (int r = 0; r < 4; ++r) {
      union { short8 s; unsigned short u[8]; } pk;
#pragma unroll
      for (int p = 0; p < 8; ++p) {
        float v = (r == 0) ? xv[p].x : (r == 1) ? xv[p].y : (r == 2) ? xv[p].z : xv[p].w;
        pk.u[p] = f2bf(fmaxf(fmaf(v, scv[p], shv[p]), 0.f));
      }
      unsigned addr = ((unsigned)(fragw << 10)) + ((((unsigned)(sub0 + r)) << 4) ^ swz);
      *(short8*)((char*)sXf + addr) = pk.s;
    }
    // ---- prefetch tile t+1 (precedes the barrier: in-place safety)
    if (tt < 1) {
#pragma unroll
      for (int p = 0; p < 8; ++p)
        xv[p] = *(const float4*)(Xb + ((size_t)(cb + p) << 13) + hbase +
                                 (tt + 1) * 64 + hq * 4);
    }
    __syncthreads();

    // ---- MFMA: 8 ds_read_b128 + 32 MFMAs per wave
    f32x4 acc[4][2];
#pragma unroll
    for (int m = 0; m < 4; ++m) {
      acc[m][0] = (f32x4){0.f, 0.f, 0.f, 0.f};
      acc[m][1] = (f32x4){0.f, 0.f, 0.f, 0.f};
    }
#pragma unroll
    for (int k = 0; k < 4; ++k) {
      short8 x0 = *(const short8*)((char*)sXf + (((wh * 2 + 0) * 4 + k) << 10) + br);
      short8 x1 = *(const short8*)((char*)sXf + (((wh * 2 + 1) * 4 + k) << 10) + br);
#pragma unroll
      for (int m = 0; m < 4; ++m) {
        acc[m][0] = __builtin_amdgcn_mfma_f32_16x16x32_bf16(wfr[m][k], x0, acc[m][0], 0, 0, 0);
        acc[m][1] = __builtin_amdgcn_mfma_f32_16x16x32_bf16(wfr[m][k], x1, acc[m][1], 0, 0, 0);
      }
    }

    // ---- epilogue: bias, store f32 [o][h], register stats accumulation
    const int ha = hbase + tt * 64 + wh * 32 + hcol;
#pragma unroll
    for (int m = 0; m < 4; ++m) {
      int obase = wo * 64 + m * 16 + og;
#pragma unroll
      for (int r = 0; r < 4; ++r) {
        int o = obase + r;
        float bv = bias[o];
        float v0 = acc[m][0][r] + bv;
        float v1 = acc[m][1][r] + bv;
        float* po = Ob + ((size_t)o << 13);
        po[ha] = v0;
        po[ha + 16] = v1;
        if (DOSTATS) {
          as_[m][r] += v0 + v1;
          aq_[m][r] = fmaf(v0, v0, fmaf(v1, v1, aq_[m][r]));
        }
      }
    }
    __syncthreads();  // guard LDS reuse by next iteration's ds_write
  }

  if (DOSTATS) {
#pragma unroll
    for (int m = 0; m < 4; ++m) {
#pragma unroll
      for (int r = 0; r < 4; ++r) {
        float s = as_[m][r], q = aq_[m][r];
#pragma unroll
        for (int mm = 1; mm <= 8; mm <<= 1) {
          s += __shfl_xor(s, mm);
          q += __shfl_xor(q, mm);
        }
        if (hcol == 0) {
          int o = wo * 64 + m * 16 + og + r;
          atomicAdd(&ssum[o], s);
          atomicAdd(&ssq[o], q);
        }
      }
    }
    __syncthreads();
    if (t < NC) {
      atomicAdd(&stats[(b * NC + t) * 2], ssum[t]);
      atomicAdd(&stats[(b * NC + t) * 2 + 1], ssq[t]);
    }
  }
}

// ---------------------------------------------------------------------------
extern "C" void kernel_launch(void* const* d_in, const int* in_sizes, int n_in,
                              void* d_out, int out_size, void* d_ws,
                              size_t ws_size, hipStream_t stream) {
  const float* corr = (const float*)d_in[0];
  const float* coh = (const float*)d_in[1];
  const float* feats = (const float*)d_in[2];
  const float* fcw = (const float*)d_in[3];
  const float* fcb = (const float*)d_in[4];
  const float* w1 = (const float*)d_in[5];
  const float* b1 = (const float*)d_in[6];
  const float* g1 = (const float*)d_in[7];
  const float* be1 = (const float*)d_in[8];
  const float* w2 = (const float*)d_in[9];
  const float* b2 = (const float*)d_in[10];
  const float* g2 = (const float*)d_in[11];
  const float* be2 = (const float*)d_in[12];

  float* out = (float*)d_out;  // agg -> x1 -> final output (in-place chain)
  float* ws = (float*)d_ws;
  float* alphab = ws;               // 131072
  float* stats1 = alphab + 131072;  // 4096
  float* stats2 = stats1 + 4096;    // 4096
  float* scale1 = stats2 + 4096;    // 2048
  float* shift1 = scale1 + 2048;    // 2048
  float* scale2 = shift1 + 2048;    // 2048
  float* shift2 = scale2 + 2048;    // 2048

  hipMemsetAsync(stats1, 0, 8192 * sizeof(float), stream);  // stats1+stats2
  alpha_kernel<<<1024, 256, 0, stream>>>(corr, coh, fcw, fcb, alphab);
  agg_kernel<<<8192, 256, 0, stream>>>(corr, feats, alphab, out, stats1);
  finalize_kernel<<<1, 128, 0, stream>>>(stats1, g1, be1, scale1, shift1);
  conv_mfma_kernel<true><<<1024, 256, 0, stream>>>(out, scale1, shift1, w1, b1,
                                                   out, stats2);
  finalize_kernel<<<1, 128, 0, stream>>>(stats2, g2, be2, scale2, shift2);
  conv_mfma_kernel<false><<<1024, 256, 0, stream>>>(out, scale2, shift2, w2,
                                                    b2, out, nullptr);
}